// Round 18
// baseline (77.338 us; speedup 1.0000x reference)
//
#include <hip/hip_runtime.h>
#include <hip/hip_bf16.h>

typedef __attribute__((ext_vector_type(8))) short bf16x8;
typedef __attribute__((ext_vector_type(4))) float f32x4;
typedef __attribute__((ext_vector_type(8))) unsigned short u16x8;

#define KD 2304
#define OUT_PER_B (256 * 1024)
#define CGPL 67600                      // 16*4225: hw-elems per cg plane (x32 ch)
#define RPL 72                          // xfn row stride (ushorts), 16B-aligned
#define PPL (65 * RPL)                  // xfn plane stride = 4680

static __device__ __forceinline__ ushort f2bf(float f) {
  union { float f; unsigned int i; } v; v.f = f;
  unsigned int x = v.i;
  x += 0x7fffu + ((x >> 16) & 1u);   // round-to-nearest-even
  return (ushort)(x >> 16);
}

#define GLDS16(gp, lp)                                                         \
  __builtin_amdgcn_global_load_lds(                                            \
      (const __attribute__((address_space(1))) void*)(gp),                     \
      (__attribute__((address_space(3))) void*)(lp), 16, 0, 0)

// swizzle: 16-B chunk g (0..15) of row r -> XOR low 3 bits with r&7 (involution)
#define SWZ(g, r) (((g) & 8) | (((g) ^ (r)) & 7))

#define CVTPK(d, lo, hi) \
  asm("v_cvt_pk_bf16_f32 %0, %1, %2" : "=v"(d) : "v"(lo), "v"(hi))

// ---------------- Kernel 1: FIR (v->h), register ring + shuffles, FLAT out ------
// No LDS, no barriers. Thread (c = lane>>3 channel, o = lane&7 w-octet).
// Output xfn[plane][h*72 + w] bf16; per c: 8 lanes x 16 B contiguous stores.
__global__ __launch_bounds__(256) void k_fir6(const float* __restrict__ x,
                                              ushort* __restrict__ xfn,
                                              const float* __restrict__ wsrc,
                                              ushort* __restrict__ wb) {
  const int band = blockIdx.x;               // 0..8; h0 = band*8
  const int cg = blockIdx.y;                 // 0..7
  const int b = blockIdx.z;                  // 0..15
  const int t = threadIdx.x;
  const int wid = t >> 6, lane = t & 63;
  const int c = lane >> 3, o = lane & 7;
  const int cw = cg * 32 + wid * 8;          // wave channel base
  const int h0 = band * 8;
  const int nrows = (band == 8) ? 1 : 8;

  // fused weight cast, grid-stride (1152 blocks x 256 thr = 294912)
  {
    int flat = band + 9 * (cg + 8 * b);
    for (int iw = flat * 256 + t; iw < 589824; iw += 294912) {
      float v = wsrc[iw];
      int j = iw % 9;
      int t2 = iw / 9;
      wb[(t2 >> 8) * KD + j * 256 + (t2 & 255)] = f2bf(v);
    }
  }

  const float* xrow = x + ((size_t)(b * 256 + cw + c) << 12) + o * 8;
  ushort* orow = xfn + (size_t)(b * 256 + cw + c) * PPL + o * 8;

  float4 rA[8], rB[8];
#define LOADR(s, r)                                                            \
  {                                                                            \
    if ((unsigned)(r) < 64u) {                                                 \
      rA[s] = *(const float4*)(xrow + (r) * 64);                               \
      rB[s] = *(const float4*)(xrow + (r) * 64 + 4);                           \
    } else {                                                                   \
      rA[s] = make_float4(0.f, 0.f, 0.f, 0.f);                                 \
      rB[s] = make_float4(0.f, 0.f, 0.f, 0.f);                                 \
    }                                                                          \
  }

  // prologue: rows h0-2 .. h0+2 into slots 6,7,0,1,2  (h0 % 8 == 0)
  LOADR(6, h0 - 2)
  LOADR(7, h0 - 1)
  LOADR(0, h0)
  LOADR(1, h0 + 1)
  LOADR(2, h0 + 2)

#pragma unroll
  for (int hh = 0; hh < 8; ++hh) {
    if (hh < nrows) {
      const int h = h0 + hh;
      LOADR((hh + 3) & 7, h + 3)

      const int sm2 = (hh + 6) & 7, sm1 = (hh + 7) & 7;
      const int s00 = hh & 7, sp1 = (hh + 1) & 7;
      float v0 = (rA[sm2].x + rA[sp1].x) + 3.f * (rA[sm1].x + rA[s00].x);
      float v1 = (rA[sm2].y + rA[sp1].y) + 3.f * (rA[sm1].y + rA[s00].y);
      float v2 = (rA[sm2].z + rA[sp1].z) + 3.f * (rA[sm1].z + rA[s00].z);
      float v3 = (rA[sm2].w + rA[sp1].w) + 3.f * (rA[sm1].w + rA[s00].w);
      float v4 = (rB[sm2].x + rB[sp1].x) + 3.f * (rB[sm1].x + rB[s00].x);
      float v5 = (rB[sm2].y + rB[sp1].y) + 3.f * (rB[sm1].y + rB[s00].y);
      float v6 = (rB[sm2].z + rB[sp1].z) + 3.f * (rB[sm1].z + rB[s00].z);
      float v7 = (rB[sm2].w + rB[sp1].w) + 3.f * (rB[sm1].w + rB[s00].w);

      float vm1 = __shfl_up(v7, 1);
      float vm2 = __shfl_up(v6, 1);
      float vp  = __shfl_down(v0, 1);
      if (o == 0) { vm1 = 0.f; vm2 = 0.f; }
      if (o == 7) vp = 0.f;

      const float S = 0.015625f;
      float g0 = ((vm2 + v1) + 3.f * (vm1 + v0)) * S;
      float g1 = ((vm1 + v2) + 3.f * (v0 + v1)) * S;
      float g2 = ((v0 + v3) + 3.f * (v1 + v2)) * S;
      float g3 = ((v1 + v4) + 3.f * (v2 + v3)) * S;
      float g4 = ((v2 + v5) + 3.f * (v3 + v4)) * S;
      float g5 = ((v3 + v6) + 3.f * (v4 + v5)) * S;
      float g6 = ((v4 + v7) + 3.f * (v5 + v6)) * S;
      float g7 = ((v5 + vp) + 3.f * (v6 + v7)) * S;

      unsigned d0, d1, d2, d3;
      CVTPK(d0, g0, g1);
      CVTPK(d1, g2, g3);
      CVTPK(d2, g4, g5);
      CVTPK(d3, g6, g7);
      *(uint4*)&orow[h * RPL] = make_uint4(d0, d1, d2, d3);
      if (o == 7)
        orow[h * RPL + 8] = f2bf((v6 + 3.f * v7) * S);  // w=64 (o*8=56 base +8)
    }
  }
}

// ---------------- Kernel 2: transpose [plane][h][w] -> plane-NHWC ---------------
// block = (h, ctile of 64ch, b): reads 64 rows of 144 B, writes 65x2x64 B.
// LDS ld[72][66] with the proven XOR col-group swizzle.
__global__ __launch_bounds__(256) void k_tr2(const ushort* __restrict__ xfn,
                                             ushort* __restrict__ xft) {
  __shared__ ushort ld[72 * 66];
  const int h = blockIdx.x;                  // 0..64
  const int c0 = blockIdx.y * 64;            // 0..3 -> 64-ch tile (2 cg planes)
  const int b = blockIdx.z;
  const int t = threadIdx.x;

  // load: 64 c x 9 chunks (w 0..71 incl pad)
#pragma unroll
  for (int it = 0; it < 3; ++it) {
    int idx = it * 256 + t;
    if (idx < 576) {
      int c = idx / 9, q = idx - c * 9;
      u16x8 v = *(const u16x8*)(xfn +
                 (size_t)(b * 256 + c0 + c) * PPL + h * RPL + q * 8);
#pragma unroll
      for (int k = 0; k < 8; ++k)
        ld[(q * 8 + k) * 66 + (c ^ (k << 3))] = v[k];
    }
  }
  __syncthreads();

  // store: 65 w x 8 a-groups -> xft[cg][b][h*65+w][32]
#pragma unroll
  for (int it = 0; it < 3; ++it) {
    int idx = it * 256 + t;
    if (idx < 520) {
      int w = idx >> 3, a = idx & 7;
      int k7 = w & 7;
      u16x8 v = *(const u16x8*)&ld[w * 66 + ((a ^ k7) << 3)];
      int cg = (c0 >> 5) + (a >> 2);
      *(u16x8*)&xft[(((size_t)(cg * 16 + b) * 4225 + h * 65 + w) << 5) +
                    (a & 3) * 8] = v;
    }
  }
}

// ---------------- Kernel 3: implicit-conv GEMM, BK=128, plane-B layout ----------
// C[oc=256][n=16384]; BM=128, BN=64, BK=128; 256 thr (4 waves 2m x 2n, 64x32 each)
// B chunk g of slice kt lives in plane cg = (kt&1)*4 + (g>>2), sub (g&3)*8.
__global__ __launch_bounds__(256) void k_gemm3(const ushort* __restrict__ Wb,
                                               const ushort* __restrict__ Xt,
                                               const float* __restrict__ bias,
                                               float* __restrict__ out) {
  __shared__ ushort lA[128 * 128];                 // 32 KB
  __shared__ ushort lB[64 * 128];                  // 16 KB
  const int bid = blockIdx.x;                      // 0..511
  const int work = (bid & 7) * 64 + (bid >> 3);    // XCD-chunked bijective
  const int ntile = work >> 1;
  const int mtile = work & 1;
  const int m0 = mtile * 128;
  const int n0 = ntile * 64;
  const int t = threadIdx.x;
  const int wid = t >> 6, lane = t & 63;
  const int wm = wid >> 1, wn = wid & 1;
  const int lrow = lane & 15, kgrp = lane >> 4;

  const ushort* aB[8];
#pragma unroll
  for (int i = 0; i < 8; ++i) {
    int idx = i * 256 + t;
    int row = idx >> 4, gL = idx & 15;
    aB[i] = Wb + (size_t)(m0 + row) * KD + SWZ(gL, row) * 8;
  }
  const ushort* bB[4];
#pragma unroll
  for (int i = 0; i < 4; ++i) {
    int idx = i * 256 + t;
    int row = idx >> 4, gL = idx & 15;
    int sg = SWZ(gL, row);
    int n = n0 + row;
    int b = n >> 10, oh = (n >> 5) & 31, ow = n & 31;
    bB[i] = Xt +
            (((size_t)((sg >> 2) * 16 + b) * 4225 + (2 * oh) * 65 + 2 * ow) << 5) +
            (sg & 3) * 8;
  }

  f32x4 acc[4][2];
#pragma unroll
  for (int i = 0; i < 4; ++i)
#pragma unroll
    for (int j = 0; j < 2; ++j) acc[i][j] = (f32x4){0.f, 0.f, 0.f, 0.f};

  for (int kt = 0; kt < 18; ++kt) {
    const int j = kt >> 1;
    const int dh = j / 3, dw = j - 3 * dh;
    const int boff = (dh * 65 + dw) * 32 + (kt & 1) * (4 * CGPL * 32);
    const int k0 = kt << 7;
    __syncthreads();
#pragma unroll
    for (int i = 0; i < 8; ++i)
      GLDS16(aB[i] + k0, &lA[(i * 256 + t) * 8]);
#pragma unroll
    for (int i = 0; i < 4; ++i)
      GLDS16(bB[i] + boff, &lB[(i * 256 + t) * 8]);
    __syncthreads();

#pragma unroll
    for (int s = 0; s < 4; ++s) {
      bf16x8 Af[4], Bf[2];
#pragma unroll
      for (int f = 0; f < 4; ++f) {
        int row = wm * 64 + f * 16 + lrow;
        Af[f] = *(const bf16x8*)&lA[row * 128 + SWZ(s * 4 + kgrp, row) * 8];
      }
#pragma unroll
      for (int f = 0; f < 2; ++f) {
        int row = wn * 32 + f * 16 + lrow;
        Bf[f] = *(const bf16x8*)&lB[row * 128 + SWZ(s * 4 + kgrp, row) * 8];
      }
#pragma unroll
      for (int fm = 0; fm < 4; ++fm)
#pragma unroll
        for (int fn = 0; fn < 2; ++fn)
          acc[fm][fn] = __builtin_amdgcn_mfma_f32_16x16x32_bf16(
              Af[fm], Bf[fn], acc[fm][fn], 0, 0, 0);
    }
  }

  f32x4 bv[4];
#pragma unroll
  for (int fm = 0; fm < 4; ++fm)
    bv[fm] = *(const f32x4*)(bias + m0 + wm * 64 + fm * 16 + kgrp * 4);

#pragma unroll
  for (int fm = 0; fm < 4; ++fm) {
#pragma unroll
    for (int fn = 0; fn < 2; ++fn) {
      int nn = n0 + wn * 32 + fn * 16 + lrow;
      int oc = m0 + wm * 64 + fm * 16 + kgrp * 4;
      float* op = out + (size_t)(nn >> 10) * OUT_PER_B + (nn & 1023) +
                  (size_t)oc * 1024;
      op[0]    = acc[fm][fn][0] + bv[fm][0];
      op[1024] = acc[fm][fn][1] + bv[fm][1];
      op[2048] = acc[fm][fn][2] + bv[fm][2];
      op[3072] = acc[fm][fn][3] + bv[fm][3];
    }
  }
}

extern "C" void kernel_launch(void* const* d_in, const int* in_sizes, int n_in,
                              void* d_out, int out_size, void* d_ws, size_t ws_size,
                              hipStream_t stream) {
  const float* x    = (const float*)d_in[0];  // [16,256,64,64]
  const float* w    = (const float*)d_in[1];  // [256,256,3,3]
  const float* bias = (const float*)d_in[2];  // [256]
  float* out = (float*)d_out;                 // [16,256,32,32]

  char* ws = (char*)d_ws;
  ushort* xfn = (ushort*)ws;                        // 4096*4680*2 = 38,338,560 B
  ushort* xft = (ushort*)(ws + 38338560);           // 34,611,200 B
  ushort* wb  = (ushort*)(ws + 38338560 + 34611200);// 1,179,648 B

  k_fir6<<<dim3(9, 8, 16), 256, 0, stream>>>(x, xfn, w, wb);
  k_tr2<<<dim3(65, 4, 16), 256, 0, stream>>>(xfn, xft);
  k_gemm3<<<512, 256, 0, stream>>>(wb, xft, bias, out);
}

// Round 19
// 72.208 us; speedup vs baseline: 1.0711x; 1.0711x over previous
//
#include <hip/hip_runtime.h>
#include <hip/hip_bf16.h>

typedef __attribute__((ext_vector_type(8))) short bf16x8;
typedef __attribute__((ext_vector_type(4))) float f32x4;
typedef __attribute__((ext_vector_type(8))) unsigned short u16x8;

#define KD 2304
#define PL 4232                      // xfn padded plane stride (elems)
#define OUT_PER_B (256 * 1024)
#define CGPL 67600                   // 16*4225 hw-elems per cg plane (x32 ch)

static __device__ __forceinline__ ushort f2bf(float f) {
  union { float f; unsigned int i; } v; v.f = f;
  unsigned int x = v.i;
  x += 0x7fffu + ((x >> 16) & 1u);   // round-to-nearest-even
  return (ushort)(x >> 16);
}

#define GLDS16(gp, lp)                                                         \
  __builtin_amdgcn_global_load_lds(                                            \
      (const __attribute__((address_space(1))) void*)(gp),                     \
      (__attribute__((address_space(3))) void*)(lp), 16, 0, 0)

// swizzle: 16-B chunk g (0..15) of row r -> XOR low 3 bits with r&7 (involution)
#define SWZ(g, r) (((g) & 8) | (((g) ^ (r)) & 7))

// ---------------- Kernel 1: separable 4x4 FIR + weight cast (R7, proven ~19us) --
__global__ __launch_bounds__(256) void k_fir(const float* __restrict__ x,
                                             ushort* __restrict__ xfn,
                                             const float* __restrict__ w,
                                             ushort* __restrict__ wb) {
  __shared__ float sxp[64 * 76];   // row r at cols 4..67; cols 2,3,68,69 zero halo
  __shared__ float stp[68 * 68];   // h-row i' at row i'+2; rows 0,1,66,67 zero
  const int plane = blockIdx.x;               // 0..4095
  const float* xp = x + (size_t)plane * 4096;
  ushort* op = xfn + (size_t)plane * PL;
  const int t = threadIdx.x;

  if (plane < 2304) {              // fused weight cast
    int iw = plane * 256 + t;
    float v = w[iw];
    int j = iw % 9;
    int t2 = iw / 9;
    int ic = t2 & 255;
    int oc = t2 >> 8;
    wb[oc * KD + j * 256 + ic] = f2bf(v);
  }

  {
    int r = t & 63, cs = t >> 6;
    int col = (cs < 2) ? (2 + cs) : (66 + cs);   // 2,3,68,69
    sxp[r * 76 + col] = 0.f;
  }
  for (int i = t; i < 272; i += 256) {           // 4 rows x 68
    int rr = i / 68, cc = i - rr * 68;
    int row = (rr < 2) ? rr : (64 + rr);         // 0,1,66,67
    stp[row * 68 + cc] = 0.f;
  }

  const float4* x4 = (const float4*)xp;
#pragma unroll
  for (int i = 0; i < 4; ++i) {
    int f4 = t + 256 * i;
    int r = f4 >> 4, w4 = f4 & 15;
    *(float4*)&sxp[r * 76 + 4 + w4 * 4] = x4[f4];
  }
  __syncthreads();

  for (int g = t; g < 1088; g += 256) {
    int i = g / 17, jg = g - i * 17;
    int j0 = jg << 2;
    const float* s = &sxp[i * 76 + j0];
    float4 a0 = *(const float4*)(s);
    float4 a1 = *(const float4*)(s + 4);
    float4 a2 = *(const float4*)(s + 8);
    float4 o;
    o.x = (a0.z + a1.y) + 3.f * (a0.w + a1.x);
    o.y = (a0.w + a1.z) + 3.f * (a1.x + a1.y);
    o.z = (a1.x + a1.w) + 3.f * (a1.y + a1.z);
    o.w = (a1.y + a2.x) + 3.f * (a1.z + a1.w);
    *(float4*)&stp[(i + 2) * 68 + j0] = o;
  }
  __syncthreads();

  for (int g = t; g < 1105; g += 256) {
    int i = g / 17, jg = g - i * 17;
    int j0 = jg << 2;
    const float* s = &stp[i * 68 + j0];
    float4 r0 = *(const float4*)(s);
    float4 r1 = *(const float4*)(s + 68);
    float4 r2 = *(const float4*)(s + 136);
    float4 r3 = *(const float4*)(s + 204);
    float4 o;
    o.x = (r0.x + r3.x) + 3.f * (r1.x + r2.x);
    o.y = (r0.y + r3.y) + 3.f * (r1.y + r2.y);
    o.z = (r0.z + r3.z) + 3.f * (r1.z + r2.z);
    o.w = (r0.w + r3.w) + 3.f * (r1.w + r2.w);
    ushort* q = op + i * 65 + j0;
    q[0] = f2bf(o.x * 0.015625f);
    if (j0 + 1 < 65) q[1] = f2bf(o.y * 0.015625f);
    if (j0 + 2 < 65) q[2] = f2bf(o.z * 0.015625f);
    if (j0 + 3 < 65) q[3] = f2bf(o.w * 0.015625f);
  }
}

// ---------------- Kernel 2: transpose flat -> plane NHWC (R6 tr, plane store) ---
// tile [64 c][128 hw]; transpose on ds_write; LDS [hw][col] stride 66,
// col-group XOR swizzle: col = c ^ ((hw&7)<<3). grid (34, 4, 16).
__global__ __launch_bounds__(256) void k_tr(const ushort* __restrict__ xfn,
                                            ushort* __restrict__ xft) {
  __shared__ ushort ld[128 * 66];
  const int hw0 = blockIdx.x * 128;
  const int c0 = blockIdx.y * 64;
  const int b = blockIdx.z;
  const int t = threadIdx.x;

#pragma unroll
  for (int it = 0; it < 4; ++it) {
    int idx = it * 256 + t;                 // 0..1023
    int c = idx >> 4, q = idx & 15;         // c 0..63, q = hw chunk
    u16x8 v = {};
    if (hw0 + q * 8 < 4225)                 // stays inside the PL=4232 row
      v = *(const u16x8*)(xfn + (size_t)(b * 256 + c0 + c) * PL + hw0 + q * 8);
#pragma unroll
    for (int k = 0; k < 8; ++k)
      ld[(q * 8 + k) * 66 + (c ^ (k << 3))] = v[k];
  }
  __syncthreads();
#pragma unroll
  for (int it = 0; it < 4; ++it) {
    int idx = it * 256 + t;
    int hwl = idx >> 3, a = idx & 7;        // hwl 0..127, a = c-group
    int k7 = hwl & 7;
    int hw = hw0 + hwl;
    if (hw < 4225) {
      u16x8 v = *(const u16x8*)&ld[hwl * 66 + ((a ^ k7) << 3)];  // 4x b32, free
      int cg = (c0 >> 5) + (a >> 2);        // plane of channel c0 + a*8
      *(u16x8*)&xft[(((size_t)(cg * 16 + b) * 4225 + hw) << 5) + (a & 3) * 8] = v;
    }
  }
}

// ---------------- Kernel 3: implicit-conv GEMM, BK=128, plane-B (R16 proven) ----
// C[oc=256][n=16384]; BM=128, BN=64, BK=128; 256 thr (4 waves 2m x 2n, 64x32 each)
// B chunk g of slice kt lives in plane cg = (kt&1)*4 + (g>>2), sub (g&3)*8.
__global__ __launch_bounds__(256) void k_gemm3(const ushort* __restrict__ Wb,
                                               const ushort* __restrict__ Xt,
                                               const float* __restrict__ bias,
                                               float* __restrict__ out) {
  __shared__ ushort lA[128 * 128];                 // 32 KB
  __shared__ ushort lB[64 * 128];                  // 16 KB
  const int bid = blockIdx.x;                      // 0..511
  const int work = (bid & 7) * 64 + (bid >> 3);    // XCD-chunked bijective
  const int ntile = work >> 1;
  const int mtile = work & 1;
  const int m0 = mtile * 128;
  const int n0 = ntile * 64;
  const int t = threadIdx.x;
  const int wid = t >> 6, lane = t & 63;
  const int wm = wid >> 1, wn = wid & 1;
  const int lrow = lane & 15, kgrp = lane >> 4;

  const ushort* aB[8];
#pragma unroll
  for (int i = 0; i < 8; ++i) {
    int idx = i * 256 + t;
    int row = idx >> 4, gL = idx & 15;
    aB[i] = Wb + (size_t)(m0 + row) * KD + SWZ(gL, row) * 8;
  }
  const ushort* bB[4];
#pragma unroll
  for (int i = 0; i < 4; ++i) {
    int idx = i * 256 + t;
    int row = idx >> 4, gL = idx & 15;
    int sg = SWZ(gL, row);
    int n = n0 + row;
    int b = n >> 10, oh = (n >> 5) & 31, ow = n & 31;
    bB[i] = Xt +
            (((size_t)((sg >> 2) * 16 + b) * 4225 + (2 * oh) * 65 + 2 * ow) << 5) +
            (sg & 3) * 8;
  }

  f32x4 acc[4][2];
#pragma unroll
  for (int i = 0; i < 4; ++i)
#pragma unroll
    for (int j = 0; j < 2; ++j) acc[i][j] = (f32x4){0.f, 0.f, 0.f, 0.f};

  for (int kt = 0; kt < 18; ++kt) {
    const int j = kt >> 1;
    const int dh = j / 3, dw = j - 3 * dh;
    const int boff = (dh * 65 + dw) * 32 + (kt & 1) * (4 * CGPL * 32);
    const int k0 = kt << 7;
    __syncthreads();
#pragma unroll
    for (int i = 0; i < 8; ++i)
      GLDS16(aB[i] + k0, &lA[(i * 256 + t) * 8]);
#pragma unroll
    for (int i = 0; i < 4; ++i)
      GLDS16(bB[i] + boff, &lB[(i * 256 + t) * 8]);
    __syncthreads();

#pragma unroll
    for (int s = 0; s < 4; ++s) {
      bf16x8 Af[4], Bf[2];
#pragma unroll
      for (int f = 0; f < 4; ++f) {
        int row = wm * 64 + f * 16 + lrow;
        Af[f] = *(const bf16x8*)&lA[row * 128 + SWZ(s * 4 + kgrp, row) * 8];
      }
#pragma unroll
      for (int f = 0; f < 2; ++f) {
        int row = wn * 32 + f * 16 + lrow;
        Bf[f] = *(const bf16x8*)&lB[row * 128 + SWZ(s * 4 + kgrp, row) * 8];
      }
#pragma unroll
      for (int fm = 0; fm < 4; ++fm)
#pragma unroll
        for (int fn = 0; fn < 2; ++fn)
          acc[fm][fn] = __builtin_amdgcn_mfma_f32_16x16x32_bf16(
              Af[fm], Bf[fn], acc[fm][fn], 0, 0, 0);
    }
  }

  f32x4 bv[4];
#pragma unroll
  for (int fm = 0; fm < 4; ++fm)
    bv[fm] = *(const f32x4*)(bias + m0 + wm * 64 + fm * 16 + kgrp * 4);

#pragma unroll
  for (int fm = 0; fm < 4; ++fm) {
#pragma unroll
    for (int fn = 0; fn < 2; ++fn) {
      int nn = n0 + wn * 32 + fn * 16 + lrow;
      int oc = m0 + wm * 64 + fm * 16 + kgrp * 4;
      float* op = out + (size_t)(nn >> 10) * OUT_PER_B + (nn & 1023) +
                  (size_t)oc * 1024;
      op[0]    = acc[fm][fn][0] + bv[fm][0];
      op[1024] = acc[fm][fn][1] + bv[fm][1];
      op[2048] = acc[fm][fn][2] + bv[fm][2];
      op[3072] = acc[fm][fn][3] + bv[fm][3];
    }
  }
}

extern "C" void kernel_launch(void* const* d_in, const int* in_sizes, int n_in,
                              void* d_out, int out_size, void* d_ws, size_t ws_size,
                              hipStream_t stream) {
  const float* x    = (const float*)d_in[0];  // [16,256,64,64]
  const float* w    = (const float*)d_in[1];  // [256,256,3,3]
  const float* bias = (const float*)d_in[2];  // [256]
  float* out = (float*)d_out;                 // [16,256,32,32]

  char* ws = (char*)d_ws;
  ushort* xfn = (ushort*)ws;                        // 4096*4232*2 = 34,668,544 B
  ushort* xft = (ushort*)(ws + 34668544);           // 34,611,200 B (plane layout)
  ushort* wb  = (ushort*)(ws + 34668544 + 34611200);// 1,179,648 B

  k_fir<<<4096, 256, 0, stream>>>(x, xfn, w, wb);
  k_tr<<<dim3(34, 4, 16), 256, 0, stream>>>(xfn, xft);
  k_gemm3<<<512, 256, 0, stream>>>(wb, xft, bias, out);
}

// Round 20
// 60.717 us; speedup vs baseline: 1.2738x; 1.1893x over previous
//
#include <hip/hip_runtime.h>
#include <hip/hip_bf16.h>

typedef __attribute__((ext_vector_type(8))) short bf16x8;
typedef __attribute__((ext_vector_type(4))) float f32x4;
typedef __attribute__((ext_vector_type(8))) unsigned short u16x8;

#define KD 2304
#define OUT_PER_B (256 * 1024)
#define HALF8 8652800                   // 16 plane8s x 16 b x 4225 x 8 elems

static __device__ __forceinline__ ushort f2bf(float f) {
  union { float f; unsigned int i; } v; v.f = f;
  unsigned int x = v.i;
  x += 0x7fffu + ((x >> 16) & 1u);   // round-to-nearest-even
  return (ushort)(x >> 16);
}

#define GLDS16(gp, lp)                                                         \
  __builtin_amdgcn_global_load_lds(                                            \
      (const __attribute__((address_space(1))) void*)(gp),                     \
      (__attribute__((address_space(3))) void*)(lp), 16, 0, 0)

// swizzle: 16-B chunk g (0..15) of row r -> XOR low 3 bits with r&7 (involution)
#define SWZ(g, r) (((g) & 8) | (((g) ^ (r)) & 7))

#define CVTPK(d, lo, hi) \
  asm("v_cvt_pk_bf16_f32 %0, %1, %2" : "=v"(d) : "v"(lo), "v"(hi))

// ---------------- Kernel 1: fused FIR(v->h) + transpose + weight cast -----------
// xft layout: [plane8=32][b=16][hw=4225][8ch] bf16 -> a wave's stores are
// CONTIGUOUS: lane hw writes 16 B at 16-B stride (16 line-txns/instr, was 64).
__global__ __launch_bounds__(256) void k_fir5(const float* __restrict__ x,
                                              ushort* __restrict__ xft,
                                              const float* __restrict__ wsrc,
                                              ushort* __restrict__ wb) {
  __shared__ ushort stageAll[4][8 * 80];     // per-wave [c][80] ushorts
  const int band = blockIdx.x;               // 0..4; h0 = band*16
  const int cg = blockIdx.y;                 // 0..7
  const int b = blockIdx.z;                  // 0..15
  const int t = threadIdx.x;
  const int wid = t >> 6, lane = t & 63;
  const int c = lane >> 3, o = lane & 7;
  const int cw = cg * 32 + wid * 8;          // wave channel base (global)
  const int h0 = band * 16;
  const int nrows = (band == 4) ? 1 : 16;
  ushort* stage = stageAll[wid];
  // output plane8 base for this wave: plane8 = cg*4 + wid
  const size_t obase = (size_t)((cg * 4 + wid) * 16 + b) * 4225;

  // fused weight cast, grid-stride (640 blocks x 256 thr)
  {
    int flat = band + 5 * (cg + 8 * b);
    for (int iw = flat * 256 + t; iw < 589824; iw += 163840) {
      float v = wsrc[iw];
      int j = iw % 9;
      int t2 = iw / 9;
      wb[(t2 >> 8) * KD + j * 256 + (t2 & 255)] = f2bf(v);
    }
  }

  const float* xrow = x + ((size_t)(b * 256 + cw + c) << 12) + o * 8;

  float4 rA[8], rB[8];
#define LOADR(s, r)                                                            \
  {                                                                            \
    if ((unsigned)(r) < 64u) {                                                 \
      rA[s] = *(const float4*)(xrow + (r) * 64);                               \
      rB[s] = *(const float4*)(xrow + (r) * 64 + 4);                           \
    } else {                                                                   \
      rA[s] = make_float4(0.f, 0.f, 0.f, 0.f);                                 \
      rB[s] = make_float4(0.f, 0.f, 0.f, 0.f);                                 \
    }                                                                          \
  }

  // prologue: rows h0-2 .. h0+2 into slots 6,7,0,1,2  (h0 % 8 == 0)
  LOADR(6, h0 - 2)
  LOADR(7, h0 - 1)
  LOADR(0, h0)
  LOADR(1, h0 + 1)
  LOADR(2, h0 + 2)

#pragma unroll
  for (int hh = 0; hh < 16; ++hh) {
    if (hh < nrows) {
      const int h = h0 + hh;
      LOADR((hh + 3) & 7, h + 3)

      const int sm2 = (hh + 6) & 7, sm1 = (hh + 7) & 7;
      const int s00 = hh & 7, sp1 = (hh + 1) & 7;
      float v0 = (rA[sm2].x + rA[sp1].x) + 3.f * (rA[sm1].x + rA[s00].x);
      float v1 = (rA[sm2].y + rA[sp1].y) + 3.f * (rA[sm1].y + rA[s00].y);
      float v2 = (rA[sm2].z + rA[sp1].z) + 3.f * (rA[sm1].z + rA[s00].z);
      float v3 = (rA[sm2].w + rA[sp1].w) + 3.f * (rA[sm1].w + rA[s00].w);
      float v4 = (rB[sm2].x + rB[sp1].x) + 3.f * (rB[sm1].x + rB[s00].x);
      float v5 = (rB[sm2].y + rB[sp1].y) + 3.f * (rB[sm1].y + rB[s00].y);
      float v6 = (rB[sm2].z + rB[sp1].z) + 3.f * (rB[sm1].z + rB[s00].z);
      float v7 = (rB[sm2].w + rB[sp1].w) + 3.f * (rB[sm1].w + rB[s00].w);

      float vm1 = __shfl_up(v7, 1);
      float vm2 = __shfl_up(v6, 1);
      float vp  = __shfl_down(v0, 1);
      if (o == 0) { vm1 = 0.f; vm2 = 0.f; }
      if (o == 7) vp = 0.f;

      const float S = 0.015625f;
      float g0 = ((vm2 + v1) + 3.f * (vm1 + v0)) * S;
      float g1 = ((vm1 + v2) + 3.f * (v0 + v1)) * S;
      float g2 = ((v0 + v3) + 3.f * (v1 + v2)) * S;
      float g3 = ((v1 + v4) + 3.f * (v2 + v3)) * S;
      float g4 = ((v2 + v5) + 3.f * (v3 + v4)) * S;
      float g5 = ((v3 + v6) + 3.f * (v4 + v5)) * S;
      float g6 = ((v4 + v7) + 3.f * (v5 + v6)) * S;
      float g7 = ((v5 + vp) + 3.f * (v6 + v7)) * S;

      unsigned d0, d1, d2, d3;
      CVTPK(d0, g0, g1);
      CVTPK(d1, g2, g3);
      CVTPK(d2, g4, g5);
      CVTPK(d3, g6, g7);
      *(uint4*)&stage[c * 80 + ((o ^ c) << 3)] = make_uint4(d0, d1, d2, d3);
      if (o == 7)
        stage[c * 80 + 64] = f2bf((v6 + 3.f * v7) * S);
      __builtin_amdgcn_wave_barrier();

      // transpose read + store: lane hw -> 16 B at 16-B stride (contiguous!)
      u16x8 pk;
#pragma unroll
      for (int cc = 0; cc < 8; ++cc)
        pk[cc] = stage[cc * 80 + (((lane >> 3) ^ cc) << 3) + (lane & 7)];
      *(u16x8*)&xft[(obase + h * 65 + lane) << 3] = pk;
      if (lane == 0) {
        u16x8 p2;
#pragma unroll
        for (int cc = 0; cc < 8; ++cc) p2[cc] = stage[cc * 80 + 64];
        *(u16x8*)&xft[(obase + h * 65 + 64) << 3] = p2;
      }
      __builtin_amdgcn_wave_barrier();
    }
  }
}

// ---------------- Kernel 2: implicit-conv GEMM, BK=128, plane8-B layout ---------
// C[oc=256][n=16384]; BM=128, BN=64, BK=128; 256 thr (4 waves 2m x 2n, 64x32 each)
// B chunk sg of slice kt lives in plane8 = (kt&1)*16 + sg (whole 16B chunk).
__global__ __launch_bounds__(256) void k_gemm3(const ushort* __restrict__ Wb,
                                               const ushort* __restrict__ Xt,
                                               const float* __restrict__ bias,
                                               float* __restrict__ out) {
  __shared__ ushort lA[128 * 128];                 // 32 KB
  __shared__ ushort lB[64 * 128];                  // 16 KB
  const int bid = blockIdx.x;                      // 0..511
  const int work = (bid & 7) * 64 + (bid >> 3);    // XCD-chunked bijective
  const int ntile = work >> 1;
  const int mtile = work & 1;
  const int m0 = mtile * 128;
  const int n0 = ntile * 64;
  const int t = threadIdx.x;
  const int wid = t >> 6, lane = t & 63;
  const int wm = wid >> 1, wn = wid & 1;
  const int lrow = lane & 15, kgrp = lane >> 4;

  const ushort* aB[8];
#pragma unroll
  for (int i = 0; i < 8; ++i) {
    int idx = i * 256 + t;
    int row = idx >> 4, gL = idx & 15;
    aB[i] = Wb + (size_t)(m0 + row) * KD + SWZ(gL, row) * 8;
  }
  const ushort* bB[4];
#pragma unroll
  for (int i = 0; i < 4; ++i) {
    int idx = i * 256 + t;
    int row = idx >> 4, gL = idx & 15;
    int sg = SWZ(gL, row);
    int n = n0 + row;
    int b = n >> 10, oh = (n >> 5) & 31, ow = n & 31;
    bB[i] = Xt + (((size_t)(sg * 16 + b) * 4225 + (2 * oh) * 65 + 2 * ow) << 3);
  }

  f32x4 acc[4][2];
#pragma unroll
  for (int i = 0; i < 4; ++i)
#pragma unroll
    for (int j = 0; j < 2; ++j) acc[i][j] = (f32x4){0.f, 0.f, 0.f, 0.f};

  for (int kt = 0; kt < 18; ++kt) {
    const int j = kt >> 1;
    const int dh = j / 3, dw = j - 3 * dh;
    const int boff = (dh * 65 + dw) * 8 + (kt & 1) * HALF8;
    const int k0 = kt << 7;
    __syncthreads();
#pragma unroll
    for (int i = 0; i < 8; ++i)
      GLDS16(aB[i] + k0, &lA[(i * 256 + t) * 8]);
#pragma unroll
    for (int i = 0; i < 4; ++i)
      GLDS16(bB[i] + boff, &lB[(i * 256 + t) * 8]);
    __syncthreads();

#pragma unroll
    for (int s = 0; s < 4; ++s) {
      bf16x8 Af[4], Bf[2];
#pragma unroll
      for (int f = 0; f < 4; ++f) {
        int row = wm * 64 + f * 16 + lrow;
        Af[f] = *(const bf16x8*)&lA[row * 128 + SWZ(s * 4 + kgrp, row) * 8];
      }
#pragma unroll
      for (int f = 0; f < 2; ++f) {
        int row = wn * 32 + f * 16 + lrow;
        Bf[f] = *(const bf16x8*)&lB[row * 128 + SWZ(s * 4 + kgrp, row) * 8];
      }
#pragma unroll
      for (int fm = 0; fm < 4; ++fm)
#pragma unroll
        for (int fn = 0; fn < 2; ++fn)
          acc[fm][fn] = __builtin_amdgcn_mfma_f32_16x16x32_bf16(
              Af[fm], Bf[fn], acc[fm][fn], 0, 0, 0);
    }
  }

  f32x4 bv[4];
#pragma unroll
  for (int fm = 0; fm < 4; ++fm)
    bv[fm] = *(const f32x4*)(bias + m0 + wm * 64 + fm * 16 + kgrp * 4);

#pragma unroll
  for (int fm = 0; fm < 4; ++fm) {
#pragma unroll
    for (int fn = 0; fn < 2; ++fn) {
      int nn = n0 + wn * 32 + fn * 16 + lrow;
      int oc = m0 + wm * 64 + fm * 16 + kgrp * 4;
      float* op = out + (size_t)(nn >> 10) * OUT_PER_B + (nn & 1023) +
                  (size_t)oc * 1024;
      op[0]    = acc[fm][fn][0] + bv[fm][0];
      op[1024] = acc[fm][fn][1] + bv[fm][1];
      op[2048] = acc[fm][fn][2] + bv[fm][2];
      op[3072] = acc[fm][fn][3] + bv[fm][3];
    }
  }
}

extern "C" void kernel_launch(void* const* d_in, const int* in_sizes, int n_in,
                              void* d_out, int out_size, void* d_ws, size_t ws_size,
                              hipStream_t stream) {
  const float* x    = (const float*)d_in[0];  // [16,256,64,64]
  const float* w    = (const float*)d_in[1];  // [256,256,3,3]
  const float* bias = (const float*)d_in[2];  // [256]
  float* out = (float*)d_out;                 // [16,256,32,32]

  char* ws = (char*)d_ws;
  ushort* xft = (ushort*)ws;                        // 32*16*4225*8*2 = 34,611,200 B
  ushort* wb  = (ushort*)(ws + 34611200);           // 1,179,648 B

  k_fir5<<<dim3(5, 8, 16), 256, 0, stream>>>(x, xft, w, wb);
  k_gemm3<<<512, 256, 0, stream>>>(wb, xft, bias, out);
}